// Round 7
// baseline (142.997 us; speedup 1.0000x reference)
//
#include <hip/hip_runtime.h>
#include <stdint.h>

typedef __bf16 bf16x8 __attribute__((ext_vector_type(8)));
typedef short  short4v __attribute__((ext_vector_type(4)));   // 4 x bf16 bits
typedef float  floatx4 __attribute__((ext_vector_type(4)));
typedef uint32_t u32x4 __attribute__((ext_vector_type(4)));

#define DI __device__ __forceinline__

// single float -> bf16 bits (compiler-native conversion, RNE)
DI uint16_t bf1(float a) {
    union { __bf16 h; uint16_t u; } r; r.h = (__bf16)a; return r.u;
}

// ---------------------------------------------------------------------------
// Kernel 1: projections via MFMA. r13: vP written in PV-fragment order so
// flash can load V operands as single contiguous 16B dwordx4 from L2:
// per 64-key tile, per o: frag f=(c2*4+quad) = keys {c2*32+quad*4+r} (r0..3)
// then {c2*32+16+quad*4+r}. XCD-clustered blk (bid & 7), matching flash.
// ---------------------------------------------------------------------------
__global__ __launch_bounds__(256) void proj_kernel(
    const float* __restrict__ x,
    const float* __restrict__ tw, const float* __restrict__ tb,
    const float* __restrict__ pw, const float* __restrict__ pb,
    const float* __restrict__ gw, const float* __restrict__ gb,
    uint16_t* __restrict__ th, uint16_t* __restrict__ phT,
    uint16_t* __restrict__ vP)
{
    __shared__ uint16_t ldsg[32 * 68];     // g-output bounce, pad 68 (8B-align ok)
    int blk = blockIdx.x & 7, nt = blockIdx.x >> 3;
    int tid = threadIdx.x, wid = tid >> 6, lane = tid & 63;
    int quad = lane >> 4, low = lane & 15;

    int b = blk & 1, q = blk >> 1, qh = q >> 1, qw = q & 1;
    int pixA = wid * 16 + low;             // pixel within 64-tile (A-row m=low)
    const float* xg = x + (size_t)b * 1048576 +
                      (size_t)(qh * 64 + nt) * 128 + qw * 64 + pixA;

    // A-frags: A0 = ch 0..31, A1 = ch 32..63;  A[m=low][k=quad*8+j]
    float a0[8], a1[8];
#pragma unroll
    for (int j = 0; j < 8; ++j) {
        a0[j] = xg[(size_t)(quad * 8 + j) * 16384];
        a1[j] = xg[(size_t)(32 + quad * 8 + j) * 16384];
    }
    bf16x8 A0, A1;
#pragma unroll
    for (int j = 0; j < 8; ++j) {
        A0[j] = (__bf16)a0[j];
        A1[j] = (__bf16)a1[j];
    }

    // one 16-o output tile: D[m=pixel][n=o0+low] = sum_c x*w + bias
    auto dotile = [&](const float* W, const float* Bv, int o0) -> floatx4 {
        floatx4 acc;
        float bias = Bv[o0 + low];
#pragma unroll
        for (int r = 0; r < 4; ++r) acc[r] = bias;
        const float* wr = W + (o0 + low) * 64 + quad * 8;   // 32B-aligned
        floatx4 w0a = *(const floatx4*)(wr);
        floatx4 w0b = *(const floatx4*)(wr + 4);
        floatx4 w1a = *(const floatx4*)(wr + 32);
        floatx4 w1b = *(const floatx4*)(wr + 36);
        bf16x8 B0, B1;
#pragma unroll
        for (int j = 0; j < 4; ++j) {
            B0[j]     = (__bf16)w0a[j];
            B0[j + 4] = (__bf16)w0b[j];
            B1[j]     = (__bf16)w1a[j];
            B1[j + 4] = (__bf16)w1b[j];
        }
        acc = __builtin_amdgcn_mfma_f32_16x16x32_bf16(A0, B0, acc, 0, 0, 0);
        acc = __builtin_amdgcn_mfma_f32_16x16x32_bf16(A1, B1, acc, 0, 0, 0);
        return acc;
    };

    // D rows: pixel = nt*64 + wid*16 + quad*4 + r; cols: o = o0 + low
    size_t thbase = ((size_t)blk * 4096 + nt * 64 + wid * 16 + quad * 4) * 32;

    floatx4 t0 = dotile(tw, tb, 0), t1 = dotile(tw, tb, 16);
#pragma unroll
    for (int r = 0; r < 4; ++r) {
        th[thbase + r * 32 + low]      = bf1(t0[r] * 1.44269504088896f);
        th[thbase + r * 32 + 16 + low] = bf1(t1[r] * 1.44269504088896f);
    }
    floatx4 p0 = dotile(pw, pb, 0), p1 = dotile(pw, pb, 16);
#pragma unroll
    for (int r = 0; r < 4; ++r) {
        phT[thbase + r * 32 + low]      = bf1(p0[r]);
        phT[thbase + r * 32 + 16 + low] = bf1(p1[r]);
    }
    floatx4 g0 = dotile(gw, gb, 0), g1 = dotile(gw, gb, 16);
#pragma unroll
    for (int r = 0; r < 4; ++r) {
        ldsg[(low)      * 68 + wid * 16 + quad * 4 + r] = bf1(g0[r]);
        ldsg[(16 + low) * 68 + wid * 16 + quad * 4 + r] = bf1(g1[r]);
    }
    __syncthreads();
    // write-out in PV-fragment order: thread -> o=tid>>3, frag f=tid&7
    {
        int o = tid >> 3, f = tid & 7;
        int c2 = f >> 2, qd = f & 3;
        const uint16_t* src = &ldsg[o * 68 + c2 * 32 + qd * 4];
        uint64_t lo = *(const uint64_t*)(src);        // keys c2*32+qd*4+0..3
        uint64_t hi = *(const uint64_t*)(src + 16);   // keys c2*32+16+qd*4+0..3
        union { uint64_t q[2]; u32x4 v; } out;
        out.q[0] = lo; out.q[1] = hi;
        *(u32x4*)(vP + (size_t)blk * 131072 + nt * 2048 + tid * 8) = out.v;
    }
}

// ---------------------------------------------------------------------------
// Kernel 2: fused attention + W-projection + BN partial sums.
// r13: NO LDS staging, NO barriers in the hot loop. K/V are XCD-L2-resident
// (512 KB/quadrant, XCD-clustered grid); fragments load straight from global
// into MFMA operand registers, double-buffered in two NAMED register sets
// (A/B — no runtime-indexed arrays, rule #20). Per 64-key tile: 8 coalesced
// dwordx4 loads + 20 MFMA + 32 exp2. Split-K x4 dual-query kept.
// LDS only for the end-of-kernel cross-split combine (37 KB).
// ---------------------------------------------------------------------------
__global__ __launch_bounds__(512, 4) void flash_kernel(
    const uint16_t* __restrict__ th, const uint16_t* __restrict__ phT,
    const uint16_t* __restrict__ vP, const float* __restrict__ w_w,
    const float* __restrict__ w_b, float* __restrict__ wy,
    float2* __restrict__ partials)
{
    __shared__ float exbuf[512 * 18];          // 36 KB combine buffer
    __shared__ float sred[2][64][2];           // 1 KB
    int blk = blockIdx.x & 7;          // XCD-clustered
    int rg  = blockIdx.x >> 3;         // 0..63
    int tid = threadIdx.x, wid = tid >> 6, lane = tid & 63;
    int sp = wid >> 1, qg = wid & 1;   // split 0..3, query-group 0..1
    int lt = tid & 127;                // thread within split (2 waves)
    int quad = lane >> 4, low = lane & 15;
    int n0 = rg * 64 + qg * 32;        // wave's 32-query base

    const uint16_t* thB = th  + (size_t)blk * 131072;
    const uint16_t* kG  = phT + (size_t)blk * 131072;
    const uint16_t* vG  = vP  + (size_t)blk * 131072;

    bf16x8 qfA = *(const bf16x8*)(thB + (n0 + low) * 32 + quad * 8);
    bf16x8 qfB = *(const bf16x8*)(thB + (n0 + 16 + low) * 32 + quad * 8);

    // fragment base pointers (u16 units); tile t adds t*2048
    const uint16_t* kBase = kG + (size_t)(sp * 1024 + low) * 32 + quad * 8;
    const uint16_t* vBase = vG + (size_t)sp * 32768 + low * 64 + quad * 8;

    floatx4 zero = {0.f, 0.f, 0.f, 0.f};
    floatx4 oaA0 = zero, oaA1 = zero, osA = zero;
    floatx4 oaB0 = zero, oaB1 = zero, osB = zero;
    union { uint32_t u[4]; bf16x8 v; } ones8;
    ones8.u[0] = 0x3F803F80u; ones8.u[1] = 0x3F803F80u;
    ones8.u[2] = 0x3F803F80u; ones8.u[3] = 0x3F803F80u;

    // two named register tile-buffers (no runtime indexing)
    bf16x8 kfA0, kfA1, kfA2, kfA3, vaA0, vaA1, vbA0, vbA1;
    bf16x8 kfB0, kfB1, kfB2, kfB3, vaB0, vaB1, vbB0, vbB1;

#define LOADT(K0, K1, K2, K3, VA0, VA1, VB0, VB1, T) {                        \
        const uint16_t* kp = kBase + (T) * 2048;                              \
        const uint16_t* vp = vBase + (T) * 2048;                              \
        K0 = *(const bf16x8*)(kp);                                            \
        K1 = *(const bf16x8*)(kp + 512);                                      \
        K2 = *(const bf16x8*)(kp + 1024);                                     \
        K3 = *(const bf16x8*)(kp + 1536);                                     \
        VA0 = *(const bf16x8*)(vp);                                           \
        VA1 = *(const bf16x8*)(vp + 32);                                      \
        VB0 = *(const bf16x8*)(vp + 1024);                                    \
        VB1 = *(const bf16x8*)(vp + 1056);                                    \
    }

#define COMPUTET(K0, K1, K2, K3, VA0, VA1, VB0, VB1) {                        \
        floatx4 saA[4], saB[4];                                               \
        saA[0] = __builtin_amdgcn_mfma_f32_16x16x32_bf16(K0, qfA, zero, 0, 0, 0); \
        saA[1] = __builtin_amdgcn_mfma_f32_16x16x32_bf16(K1, qfA, zero, 0, 0, 0); \
        saA[2] = __builtin_amdgcn_mfma_f32_16x16x32_bf16(K2, qfA, zero, 0, 0, 0); \
        saA[3] = __builtin_amdgcn_mfma_f32_16x16x32_bf16(K3, qfA, zero, 0, 0, 0); \
        saB[0] = __builtin_amdgcn_mfma_f32_16x16x32_bf16(K0, qfB, zero, 0, 0, 0); \
        saB[1] = __builtin_amdgcn_mfma_f32_16x16x32_bf16(K1, qfB, zero, 0, 0, 0); \
        saB[2] = __builtin_amdgcn_mfma_f32_16x16x32_bf16(K2, qfB, zero, 0, 0, 0); \
        saB[3] = __builtin_amdgcn_mfma_f32_16x16x32_bf16(K3, qfB, zero, 0, 0, 0); \
        union { __bf16 h[8]; bf16x8 v; } PA[2], PB[2];                        \
        _Pragma("unroll")                                                     \
        for (int c2 = 0; c2 < 2; ++c2) {                                      \
            _Pragma("unroll")                                                 \
            for (int j = 0; j < 4; ++j) {                                     \
                PA[c2].h[j]     = (__bf16)__builtin_amdgcn_exp2f(saA[2*c2][j]);     \
                PA[c2].h[4 + j] = (__bf16)__builtin_amdgcn_exp2f(saA[2*c2 + 1][j]); \
                PB[c2].h[j]     = (__bf16)__builtin_amdgcn_exp2f(saB[2*c2][j]);     \
                PB[c2].h[4 + j] = (__bf16)__builtin_amdgcn_exp2f(saB[2*c2 + 1][j]); \
            }                                                                 \
        }                                                                     \
        oaA0 = __builtin_amdgcn_mfma_f32_16x16x32_bf16(VA0, PA[0].v, oaA0, 0, 0, 0); \
        oaA1 = __builtin_amdgcn_mfma_f32_16x16x32_bf16(VB0, PA[0].v, oaA1, 0, 0, 0); \
        osA  = __builtin_amdgcn_mfma_f32_16x16x32_bf16(ones8.v, PA[0].v, osA, 0, 0, 0); \
        oaA0 = __builtin_amdgcn_mfma_f32_16x16x32_bf16(VA1, PA[1].v, oaA0, 0, 0, 0); \
        oaA1 = __builtin_amdgcn_mfma_f32_16x16x32_bf16(VB1, PA[1].v, oaA1, 0, 0, 0); \
        osA  = __builtin_amdgcn_mfma_f32_16x16x32_bf16(ones8.v, PA[1].v, osA, 0, 0, 0); \
        oaB0 = __builtin_amdgcn_mfma_f32_16x16x32_bf16(VA0, PB[0].v, oaB0, 0, 0, 0); \
        oaB1 = __builtin_amdgcn_mfma_f32_16x16x32_bf16(VB0, PB[0].v, oaB1, 0, 0, 0); \
        osB  = __builtin_amdgcn_mfma_f32_16x16x32_bf16(ones8.v, PB[0].v, osB, 0, 0, 0); \
        oaB0 = __builtin_amdgcn_mfma_f32_16x16x32_bf16(VA1, PB[1].v, oaB0, 0, 0, 0); \
        oaB1 = __builtin_amdgcn_mfma_f32_16x16x32_bf16(VB1, PB[1].v, oaB1, 0, 0, 0); \
        osB  = __builtin_amdgcn_mfma_f32_16x16x32_bf16(ones8.v, PB[1].v, osB, 0, 0, 0); \
    }

    LOADT(kfA0, kfA1, kfA2, kfA3, vaA0, vaA1, vbA0, vbA1, 0);
    for (int t = 0; t < 16; t += 2) {
        LOADT(kfB0, kfB1, kfB2, kfB3, vaB0, vaB1, vbB0, vbB1, t + 1);
        COMPUTET(kfA0, kfA1, kfA2, kfA3, vaA0, vaA1, vbA0, vbA1);
        if (t < 14)
            LOADT(kfA0, kfA1, kfA2, kfA3, vaA0, vaA1, vbA0, vbA1, t + 2);
        COMPUTET(kfB0, kfB1, kfB2, kfB3, vaB0, vaB1, vbB0, vbB1);
    }
#undef LOADT
#undef COMPUTET

    // ---- cross-split combine: 18 floats/thread via LDS ----
    {
        int li = tid * 18;
#pragma unroll
        for (int r = 0; r < 4; ++r) {
            exbuf[li + r]      = oaA0[r];
            exbuf[li + 4 + r]  = oaA1[r];
            exbuf[li + 9 + r]  = oaB0[r];
            exbuf[li + 13 + r] = oaB1[r];
        }
        exbuf[li + 8]  = osA[0];
        exbuf[li + 17] = osB[0];
    }
    __syncthreads();
    floatx4 cA0 = zero, cA1 = zero, cB0 = zero, cB1 = zero;
    float cosA = 0.f, cosB = 0.f;
#pragma unroll
    for (int s = 0; s < 4; ++s) {
        const float* p = exbuf + (s * 128 + lt) * 18;
#pragma unroll
        for (int r = 0; r < 4; ++r) {
            cA0[r] += p[r];
            cA1[r] += p[4 + r];
            cB0[r] += p[9 + r];
            cB1[r] += p[13 + r];
        }
        cosA += p[8];
        cosB += p[17];
    }

    // ---- epilogue: normalize, W-projection via one 16x16x32 MFMA each ----
    float rinvA = 1.0f / cosA, rinvB = 1.0f / cosB;
    union { __bf16 h[8]; bf16x8 v; } YA8, YB8;
#pragma unroll
    for (int r = 0; r < 4; ++r) {
        YA8.h[r]     = (__bf16)(cA0[r] * rinvA);
        YA8.h[4 + r] = (__bf16)(cA1[r] * rinvA);
        YB8.h[r]     = (__bf16)(cB0[r] * rinvB);
        YB8.h[4 + r] = (__bf16)(cB1[r] * rinvB);
    }

    float* wyB = wy + (size_t)blk * 262144;
    int nA = n0 + low, nB = n0 + 16 + low;
    int ct = sp;
    {
        floatx4 accA, accB;
#pragma unroll
        for (int r = 0; r < 4; ++r) {
            accA[r] = w_b[ct * 16 + quad * 4 + r];
            accB[r] = accA[r];
        }
        floatx4 w0 = *(const floatx4*)(w_w + (ct * 16 + low) * 32 + quad * 4);
        floatx4 w1 = *(const floatx4*)(w_w + (ct * 16 + low) * 32 + 16 + quad * 4);
        union { __bf16 h[8]; bf16x8 v; } W8;
#pragma unroll
        for (int r = 0; r < 4; ++r) {
            W8.h[r]     = (__bf16)w0[r];
            W8.h[4 + r] = (__bf16)w1[r];
        }
        accA = __builtin_amdgcn_mfma_f32_16x16x32_bf16(W8.v, YA8.v, accA, 0, 0, 0);
        accB = __builtin_amdgcn_mfma_f32_16x16x32_bf16(W8.v, YB8.v, accB, 0, 0, 0);
#pragma unroll
        for (int r = 0; r < 4; ++r) {
            int ch = ct * 16 + quad * 4 + r;
            wyB[(size_t)ch * 4096 + nA] = accA[r];
            wyB[(size_t)ch * 4096 + nB] = accB[r];
            float s = accA[r] + accB[r];
            float ss = accA[r] * accA[r] + accB[r] * accB[r];
            s += __shfl_xor(s, 1); ss += __shfl_xor(ss, 1);
            s += __shfl_xor(s, 2); ss += __shfl_xor(ss, 2);
            s += __shfl_xor(s, 4); ss += __shfl_xor(ss, 4);
            s += __shfl_xor(s, 8); ss += __shfl_xor(ss, 8);
            if (low == 0) {
                sred[qg][ch][0] = s;
                sred[qg][ch][1] = ss;
            }
        }
    }
    __syncthreads();
    if (tid < 64) {
        float s  = sred[0][tid][0] + sred[1][tid][0];
        float ss = sred[0][tid][1] + sred[1][tid][1];
        partials[((size_t)blk * 64 + rg) * 64 + tid] = make_float2(s, ss);
    }
}

// ---------------------------------------------------------------------------
// Kernel 3: BN stats — grid 256 = (q<<6)|c, block 64 (one thread per rg).
// ---------------------------------------------------------------------------
__global__ __launch_bounds__(64) void stats_kernel(
    const float2* __restrict__ partials, const float* __restrict__ gamma,
    const float* __restrict__ beta, float2* __restrict__ stats)
{
    int q = blockIdx.x >> 6, c = blockIdx.x & 63;
    int t = threadIdx.x;                       // rg
    float2 p0 = partials[(((size_t)(q * 2 + 0)) * 64 + t) * 64 + c];
    float2 p1 = partials[(((size_t)(q * 2 + 1)) * 64 + t) * 64 + c];
    float S = p0.x + p1.x, SS = p0.y + p1.y;
    S += __shfl_xor(S, 1);  SS += __shfl_xor(SS, 1);
    S += __shfl_xor(S, 2);  SS += __shfl_xor(SS, 2);
    S += __shfl_xor(S, 4);  SS += __shfl_xor(SS, 4);
    S += __shfl_xor(S, 8);  SS += __shfl_xor(SS, 8);
    S += __shfl_xor(S, 16); SS += __shfl_xor(SS, 16);
    S += __shfl_xor(S, 32); SS += __shfl_xor(SS, 32);
    if (t == 0) {
        float mu  = S * (1.0f / 8192.0f);
        float var = SS * (1.0f / 8192.0f) - mu * mu;
        float scale = gamma[c] * rsqrtf(var + 1e-5f);
        float shift = beta[c] - mu * scale;
        stats[q * 64 + c] = make_float2(scale, shift);
    }
}

// ---------------------------------------------------------------------------
// Kernel 4: out = (wy * scale + shift) + x. XCD-clustered (bid & 7 = blk).
// ---------------------------------------------------------------------------
__global__ __launch_bounds__(256) void final_kernel(
    const float* __restrict__ wy, const float2* __restrict__ stats,
    const float* __restrict__ x, float* __restrict__ out)
{
    int bid = blockIdx.x;
    size_t base = (((size_t)(bid & 7) * 256 + (bid >> 3)) * 256 + threadIdx.x) * 4;
    int n   = (int)(base & 4095);
    int c   = (int)((base >> 12) & 63);
    int blk = (int)(base >> 18);
    int b = blk & 1, q = blk >> 1, qh = q >> 1, qw = q & 1;
    int i = n >> 6, j = n & 63;
    float2 sc = stats[q * 64 + c];
    floatx4 wv = *(const floatx4*)(wy + base);
    size_t xa = ((size_t)(b * 64 + c) * 128 + (qh * 64 + i)) * 128 + qw * 64 + j;
    floatx4 xv = *(const floatx4*)(x + xa);
    floatx4 ov;
#pragma unroll
    for (int k = 0; k < 4; ++k) ov[k] = wv[k] * sc.x + sc.y + xv[k];
    *(floatx4*)(out + xa) = ov;
}

// ---------------------------------------------------------------------------
extern "C" void kernel_launch(void* const* d_in, const int* in_sizes, int n_in,
                              void* d_out, int out_size, void* d_ws, size_t ws_size,
                              hipStream_t stream)
{
    const float* x       = (const float*)d_in[0];
    const float* g_w     = (const float*)d_in[1];
    const float* g_b     = (const float*)d_in[2];
    const float* theta_w = (const float*)d_in[3];
    const float* theta_b = (const float*)d_in[4];
    const float* phi_w   = (const float*)d_in[5];
    const float* phi_b   = (const float*)d_in[6];
    const float* w_w     = (const float*)d_in[7];
    const float* w_b     = (const float*)d_in[8];
    const float* gamma   = (const float*)d_in[9];
    const float* beta    = (const float*)d_in[10];

    char* ws = (char*)d_ws;
    uint16_t* th       = (uint16_t*)(ws);                 // 0 .. 2M
    uint16_t* phT      = (uint16_t*)(ws + (2u << 20));    // 2 .. 4M
    uint16_t* vP       = (uint16_t*)(ws + (4u << 20));    // 4 .. 6M
    float*    wy       = (float*)(ws + (6u << 20));       // 6 .. 14M
    float2*   partials = (float2*)(ws + (14u << 20));     // 256 KB
    float2*   stats    = (float2*)(ws + (14u << 20) + (1u << 18));

    proj_kernel  <<<512,  256, 0, stream>>>(x, theta_w, theta_b, phi_w, phi_b,
                                            g_w, g_b, th, phT, vP);
    flash_kernel <<<512,  512, 0, stream>>>(th, phT, vP, w_w, w_b, wy, partials);
    stats_kernel <<<256,  64,  0, stream>>>(partials, gamma, beta, stats);
    final_kernel <<<2048, 256, 0, stream>>>(wy, stats, x, (float*)d_out);
}

// Round 9
// 123.609 us; speedup vs baseline: 1.1568x; 1.1568x over previous
//
#include <hip/hip_runtime.h>
#include <stdint.h>

typedef __bf16 bf16x8 __attribute__((ext_vector_type(8)));
typedef short  short4v __attribute__((ext_vector_type(4)));   // 4 x bf16 bits
typedef float  floatx4 __attribute__((ext_vector_type(4)));
typedef uint32_t u32x4 __attribute__((ext_vector_type(4)));

#define DI __device__ __forceinline__

// single float -> bf16 bits (compiler-native conversion, RNE)
DI uint16_t bf1(float a) {
    union { __bf16 h; uint16_t u; } r; r.h = (__bf16)a; return r.u;
}

// ---------------------------------------------------------------------------
// Kernel 1: projections via MFMA. r15: 512-thread WGs, 8 waves =
// (o-half x pixel-quarter). Each wave does 3 dotiles (theta/phi/g) for one
// 16-channel o-half instead of 6 for both: serial chain halves, occupancy
// 2 -> 4 waves/SIMD. A-frags duplicated across o-half wave pairs (x traffic
// 8->16 MB, L3-absorbed). Layouts identical to the r12-green version.
// XCD-clustered blk (bid & 7), matching flash.
// ---------------------------------------------------------------------------
__global__ __launch_bounds__(512) void proj_kernel(
    const float* __restrict__ x,
    const float* __restrict__ tw, const float* __restrict__ tb,
    const float* __restrict__ pw, const float* __restrict__ pb,
    const float* __restrict__ gw, const float* __restrict__ gb,
    uint16_t* __restrict__ th, uint16_t* __restrict__ phT,
    uint16_t* __restrict__ vP)
{
    __shared__ uint16_t ldsg[32 * 68];     // g-output bounce, pad 68 (8B-align ok)
    int blk = blockIdx.x & 7, nt = blockIdx.x >> 3;
    int tid = threadIdx.x, wid = tid >> 6, lane = tid & 63;
    int quad = lane >> 4, low = lane & 15;
    int pwv = wid & 3, oh = wid >> 2;      // pixel-quarter 0..3, o-half 0..1

    int b = blk & 1, q = blk >> 1, qh = q >> 1, qw = q & 1;
    int pixA = pwv * 16 + low;             // pixel within 64-tile (A-row m=low)
    const float* xg = x + (size_t)b * 1048576 +
                      (size_t)(qh * 64 + nt) * 128 + qw * 64 + pixA;

    // A-frags: A0 = ch 0..31, A1 = ch 32..63;  A[m=low][k=quad*8+j]
    float a0[8], a1[8];
#pragma unroll
    for (int j = 0; j < 8; ++j) {
        a0[j] = xg[(size_t)(quad * 8 + j) * 16384];
        a1[j] = xg[(size_t)(32 + quad * 8 + j) * 16384];
    }
    bf16x8 A0, A1;
#pragma unroll
    for (int j = 0; j < 8; ++j) {
        A0[j] = (__bf16)a0[j];
        A1[j] = (__bf16)a1[j];
    }

    int o = oh * 16 + low;                 // this wave's output channel
    // one 16-o output tile: D[m=pixel][n=o] = sum_c x*w + bias
    auto dotile = [&](const float* W, const float* Bv) -> floatx4 {
        floatx4 acc;
        float bias = Bv[o];
#pragma unroll
        for (int r = 0; r < 4; ++r) acc[r] = bias;
        const float* wr = W + o * 64 + quad * 8;   // 32B-aligned
        floatx4 w0a = *(const floatx4*)(wr);
        floatx4 w0b = *(const floatx4*)(wr + 4);
        floatx4 w1a = *(const floatx4*)(wr + 32);
        floatx4 w1b = *(const floatx4*)(wr + 36);
        bf16x8 B0, B1;
#pragma unroll
        for (int j = 0; j < 4; ++j) {
            B0[j]     = (__bf16)w0a[j];
            B0[j + 4] = (__bf16)w0b[j];
            B1[j]     = (__bf16)w1a[j];
            B1[j + 4] = (__bf16)w1b[j];
        }
        acc = __builtin_amdgcn_mfma_f32_16x16x32_bf16(A0, B0, acc, 0, 0, 0);
        acc = __builtin_amdgcn_mfma_f32_16x16x32_bf16(A1, B1, acc, 0, 0, 0);
        return acc;
    };

    // D rows: pixel = nt*64 + pwv*16 + quad*4 + r; col: o
    size_t thbase = ((size_t)blk * 4096 + nt * 64 + pwv * 16 + quad * 4) * 32;

    floatx4 t0 = dotile(tw, tb);
#pragma unroll
    for (int r = 0; r < 4; ++r)
        th[thbase + r * 32 + o] = bf1(t0[r] * 1.44269504088896f);
    floatx4 p0 = dotile(pw, pb);
#pragma unroll
    for (int r = 0; r < 4; ++r)
        phT[thbase + r * 32 + o] = bf1(p0[r]);
    floatx4 g0 = dotile(gw, gb);
#pragma unroll
    for (int r = 0; r < 4; ++r)
        ldsg[o * 68 + pwv * 16 + quad * 4 + r] = bf1(g0[r]);
    __syncthreads();
    // coalesced write-out: thread -> 16B of vP [o=tid>>3][k=(tid&7)*8]
    if (tid < 256) {
        int oo = tid >> 3, k = (tid & 7) * 8;
        const uint16_t* src = &ldsg[oo * 68 + k];
        uint64_t lo = *(const uint64_t*)(src);       // 8B-aligned
        uint64_t hi = *(const uint64_t*)(src + 4);
        union { uint64_t q2[2]; u32x4 v; } out;
        out.q2[0] = lo; out.q2[1] = hi;
        *(u32x4*)(vP + (size_t)blk * 131072 + nt * 2048 + tid * 8) = out.v;
    }
}

// ---------------------------------------------------------------------------
// Kernel 2: fused attention + W-projection + BN partial sums.
// r12 structure verbatim (best green: split-K x4 dual-query, LDS staging as
// the L2-multicast layer, PV widened to 16x16x32 via fragment concat).
// ---------------------------------------------------------------------------
__global__ __launch_bounds__(512, 4) void flash_kernel(
    const uint16_t* __restrict__ th, const uint16_t* __restrict__ phT,
    const uint16_t* __restrict__ vP, const float* __restrict__ w_w,
    const float* __restrict__ w_b, float* __restrict__ wy,
    float2* __restrict__ partials)
{
    __shared__ uint16_t ldsK[4][2][64 * 40];   // [split][buf] 40 KB
    __shared__ uint16_t ldsV[4][2][32 * 72];   // [split][buf] 36 KB
    __shared__ float sred[2][64][2];           // 1 KB  (total ~78 KB -> 2 WG/CU)
    int blk = blockIdx.x & 7;          // XCD-clustered
    int rg  = blockIdx.x >> 3;         // 0..63
    int tid = threadIdx.x, wid = tid >> 6, lane = tid & 63;
    int sp = wid >> 1, qg = wid & 1;   // split 0..3, query-group 0..1
    int lt = tid & 127;                // thread within split (2 waves)
    int quad = lane >> 4, low = lane & 15;
    int n0 = rg * 64 + qg * 32;        // wave's 32-query base

    const uint16_t* thB = th  + (size_t)blk * 131072;
    const uint16_t* kG  = phT + (size_t)blk * 131072;
    const uint16_t* vG  = vP  + (size_t)blk * 131072;

    bf16x8 qfA = *(const bf16x8*)(thB + (n0 + low) * 32 + quad * 8);
    bf16x8 qfB = *(const bf16x8*)(thB + (n0 + 16 + low) * 32 + quad * 8);

    const u32x4* kSrc = (const u32x4*)kG + sp * 4096 + lt;
    const u32x4* vSrc = (const u32x4*)vG + sp * 4096 + lt;
    const int kW0 = ((lt >> 2)) * 40 + (lt & 3) * 8;        // rows 0..31
    const int kW1 = (32 + (lt >> 2)) * 40 + (lt & 3) * 8;   // rows 32..63
    const int vW0 = ((lt >> 3)) * 72 + (lt & 7) * 8;        // o 0..15
    const int vW1 = (16 + (lt >> 3)) * 72 + (lt & 7) * 8;   // o 16..31

    u32x4 kr0 = kSrc[0], kr1 = kSrc[128];
    u32x4 vr0 = vSrc[0], vr1 = vSrc[128];
    *(u32x4*)(&ldsK[sp][0][kW0]) = kr0;  *(u32x4*)(&ldsK[sp][0][kW1]) = kr1;
    *(u32x4*)(&ldsV[sp][0][vW0]) = vr0;  *(u32x4*)(&ldsV[sp][0][vW1]) = vr1;
    __syncthreads();

    floatx4 zero = {0.f, 0.f, 0.f, 0.f};
    floatx4 oaA0 = zero, oaA1 = zero, osA = zero;
    floatx4 oaB0 = zero, oaB1 = zero, osB = zero;
    union { uint32_t u[4]; bf16x8 v; } ones8;
    ones8.u[0] = 0x3F803F80u; ones8.u[1] = 0x3F803F80u;
    ones8.u[2] = 0x3F803F80u; ones8.u[3] = 0x3F803F80u;

    for (int t = 0; t < 16; ++t) {
        int buf = t & 1;
        if (t < 15) {
            kr0 = kSrc[(t + 1) * 256];  kr1 = kSrc[(t + 1) * 256 + 128];
            vr0 = vSrc[(t + 1) * 256];  vr1 = vSrc[(t + 1) * 256 + 128];
        }
        const uint16_t* Kb = ldsK[sp][buf];
        const uint16_t* Vb = ldsV[sp][buf];
        bf16x8 kf[4];
        union { short4v s[2]; bf16x8 v; } vA2[2], vB2[2];
#pragma unroll
        for (int c = 0; c < 4; ++c)
            kf[c] = *(const bf16x8*)(Kb + (c * 16 + low) * 40 + quad * 8);
#pragma unroll
        for (int c2 = 0; c2 < 2; ++c2) {
            vA2[c2].s[0] = *(const short4v*)(Vb + low * 72 + (2*c2)     * 16 + quad * 4);
            vA2[c2].s[1] = *(const short4v*)(Vb + low * 72 + (2*c2 + 1) * 16 + quad * 4);
            vB2[c2].s[0] = *(const short4v*)(Vb + (16 + low) * 72 + (2*c2)     * 16 + quad * 4);
            vB2[c2].s[1] = *(const short4v*)(Vb + (16 + low) * 72 + (2*c2 + 1) * 16 + quad * 4);
        }
        // ---- group A ----
        {
            floatx4 sa[4];
#pragma unroll
            for (int c = 0; c < 4; ++c)
                sa[c] = __builtin_amdgcn_mfma_f32_16x16x32_bf16(kf[c], qfA, zero, 0, 0, 0);
            union { __bf16 h[8]; bf16x8 v; } P2[2];
#pragma unroll
            for (int c2 = 0; c2 < 2; ++c2) {
#pragma unroll
                for (int j = 0; j < 4; ++j) {
                    P2[c2].h[j]     = (__bf16)__builtin_amdgcn_exp2f(sa[2*c2][j]);
                    P2[c2].h[4 + j] = (__bf16)__builtin_amdgcn_exp2f(sa[2*c2 + 1][j]);
                }
            }
#pragma unroll
            for (int c2 = 0; c2 < 2; ++c2) {
                oaA0 = __builtin_amdgcn_mfma_f32_16x16x32_bf16(vA2[c2].v, P2[c2].v, oaA0, 0, 0, 0);
                oaA1 = __builtin_amdgcn_mfma_f32_16x16x32_bf16(vB2[c2].v, P2[c2].v, oaA1, 0, 0, 0);
                osA  = __builtin_amdgcn_mfma_f32_16x16x32_bf16(ones8.v,   P2[c2].v, osA,  0, 0, 0);
            }
        }
        // ---- group B ----
        {
            floatx4 sa[4];
#pragma unroll
            for (int c = 0; c < 4; ++c)
                sa[c] = __builtin_amdgcn_mfma_f32_16x16x32_bf16(kf[c], qfB, zero, 0, 0, 0);
            union { __bf16 h[8]; bf16x8 v; } P2[2];
#pragma unroll
            for (int c2 = 0; c2 < 2; ++c2) {
#pragma unroll
                for (int j = 0; j < 4; ++j) {
                    P2[c2].h[j]     = (__bf16)__builtin_amdgcn_exp2f(sa[2*c2][j]);
                    P2[c2].h[4 + j] = (__bf16)__builtin_amdgcn_exp2f(sa[2*c2 + 1][j]);
                }
            }
#pragma unroll
            for (int c2 = 0; c2 < 2; ++c2) {
                oaB0 = __builtin_amdgcn_mfma_f32_16x16x32_bf16(vA2[c2].v, P2[c2].v, oaB0, 0, 0, 0);
                oaB1 = __builtin_amdgcn_mfma_f32_16x16x32_bf16(vB2[c2].v, P2[c2].v, oaB1, 0, 0, 0);
                osB  = __builtin_amdgcn_mfma_f32_16x16x32_bf16(ones8.v,   P2[c2].v, osB,  0, 0, 0);
            }
        }
        if (t < 15) {
            *(u32x4*)(&ldsK[sp][buf ^ 1][kW0]) = kr0;
            *(u32x4*)(&ldsK[sp][buf ^ 1][kW1]) = kr1;
            *(u32x4*)(&ldsV[sp][buf ^ 1][vW0]) = vr0;
            *(u32x4*)(&ldsV[sp][buf ^ 1][vW1]) = vr1;
        }
        __syncthreads();
    }

    // ---- cross-split combine: 18 floats/thread via reused K-LDS ----
    {
        float* exW = (float*)(&ldsK[0][0][0]);   // 512*18*4B = 36864B <= 40960B
        int li = tid * 18;
#pragma unroll
        for (int r = 0; r < 4; ++r) {
            exW[li + r]      = oaA0[r];
            exW[li + 4 + r]  = oaA1[r];
            exW[li + 9 + r]  = oaB0[r];
            exW[li + 13 + r] = oaB1[r];
        }
        exW[li + 8]  = osA[0];
        exW[li + 17] = osB[0];
    }
    __syncthreads();
    floatx4 cA0 = zero, cA1 = zero, cB0 = zero, cB1 = zero;
    float cosA = 0.f, cosB = 0.f;
    {
        const float* exR = (const float*)(&ldsK[0][0][0]);
#pragma unroll
        for (int s = 0; s < 4; ++s) {
            const float* p = exR + (s * 128 + lt) * 18;
#pragma unroll
            for (int r = 0; r < 4; ++r) {
                cA0[r] += p[r];
                cA1[r] += p[4 + r];
                cB0[r] += p[9 + r];
                cB1[r] += p[13 + r];
            }
            cosA += p[8];
            cosB += p[17];
        }
    }

    // ---- epilogue: normalize, W-projection via one 16x16x32 MFMA each ----
    float rinvA = 1.0f / cosA, rinvB = 1.0f / cosB;
    union { __bf16 h[8]; bf16x8 v; } YA8, YB8;
#pragma unroll
    for (int r = 0; r < 4; ++r) {
        YA8.h[r]     = (__bf16)(cA0[r] * rinvA);
        YA8.h[4 + r] = (__bf16)(cA1[r] * rinvA);
        YB8.h[r]     = (__bf16)(cB0[r] * rinvB);
        YB8.h[4 + r] = (__bf16)(cB1[r] * rinvB);
    }

    float* wyB = wy + (size_t)blk * 262144;
    int nA = n0 + low, nB = n0 + 16 + low;
    int ct = sp;
    {
        floatx4 accA, accB;
#pragma unroll
        for (int r = 0; r < 4; ++r) {
            accA[r] = w_b[ct * 16 + quad * 4 + r];
            accB[r] = accA[r];
        }
        floatx4 w0 = *(const floatx4*)(w_w + (ct * 16 + low) * 32 + quad * 4);
        floatx4 w1 = *(const floatx4*)(w_w + (ct * 16 + low) * 32 + 16 + quad * 4);
        union { __bf16 h[8]; bf16x8 v; } W8;
#pragma unroll
        for (int r = 0; r < 4; ++r) {
            W8.h[r]     = (__bf16)w0[r];
            W8.h[4 + r] = (__bf16)w1[r];
        }
        accA = __builtin_amdgcn_mfma_f32_16x16x32_bf16(W8.v, YA8.v, accA, 0, 0, 0);
        accB = __builtin_amdgcn_mfma_f32_16x16x32_bf16(W8.v, YB8.v, accB, 0, 0, 0);
#pragma unroll
        for (int r = 0; r < 4; ++r) {
            int ch = ct * 16 + quad * 4 + r;
            wyB[(size_t)ch * 4096 + nA] = accA[r];
            wyB[(size_t)ch * 4096 + nB] = accB[r];
            float s = accA[r] + accB[r];
            float ss = accA[r] * accA[r] + accB[r] * accB[r];
            s += __shfl_xor(s, 1); ss += __shfl_xor(ss, 1);
            s += __shfl_xor(s, 2); ss += __shfl_xor(ss, 2);
            s += __shfl_xor(s, 4); ss += __shfl_xor(ss, 4);
            s += __shfl_xor(s, 8); ss += __shfl_xor(ss, 8);
            if (low == 0) {
                sred[qg][ch][0] = s;
                sred[qg][ch][1] = ss;
            }
        }
    }
    __syncthreads();
    if (tid < 64) {
        float s  = sred[0][tid][0] + sred[1][tid][0];
        float ss = sred[0][tid][1] + sred[1][tid][1];
        partials[((size_t)blk * 64 + rg) * 64 + tid] = make_float2(s, ss);
    }
}

// ---------------------------------------------------------------------------
// Kernel 3: BN stats — grid 256 = (q<<6)|c, block 64 (one thread per rg).
// ---------------------------------------------------------------------------
__global__ __launch_bounds__(64) void stats_kernel(
    const float2* __restrict__ partials, const float* __restrict__ gamma,
    const float* __restrict__ beta, float2* __restrict__ stats)
{
    int q = blockIdx.x >> 6, c = blockIdx.x & 63;
    int t = threadIdx.x;                       // rg
    float2 p0 = partials[(((size_t)(q * 2 + 0)) * 64 + t) * 64 + c];
    float2 p1 = partials[(((size_t)(q * 2 + 1)) * 64 + t) * 64 + c];
    float S = p0.x + p1.x, SS = p0.y + p1.y;
    S += __shfl_xor(S, 1);  SS += __shfl_xor(SS, 1);
    S += __shfl_xor(S, 2);  SS += __shfl_xor(SS, 2);
    S += __shfl_xor(S, 4);  SS += __shfl_xor(SS, 4);
    S += __shfl_xor(S, 8);  SS += __shfl_xor(SS, 8);
    S += __shfl_xor(S, 16); SS += __shfl_xor(SS, 16);
    S += __shfl_xor(S, 32); SS += __shfl_xor(SS, 32);
    if (t == 0) {
        float mu  = S * (1.0f / 8192.0f);
        float var = SS * (1.0f / 8192.0f) - mu * mu;
        float scale = gamma[c] * rsqrtf(var + 1e-5f);
        float shift = beta[c] - mu * scale;
        stats[q * 64 + c] = make_float2(scale, shift);
    }
}

// ---------------------------------------------------------------------------
// Kernel 4: out = (wy * scale + shift) + x. XCD-clustered (bid & 7 = blk).
// ---------------------------------------------------------------------------
__global__ __launch_bounds__(256) void final_kernel(
    const float* __restrict__ wy, const float2* __restrict__ stats,
    const float* __restrict__ x, float* __restrict__ out)
{
    int bid = blockIdx.x;
    size_t base = (((size_t)(bid & 7) * 256 + (bid >> 3)) * 256 + threadIdx.x) * 4;
    int n   = (int)(base & 4095);
    int c   = (int)((base >> 12) & 63);
    int blk = (int)(base >> 18);
    int b = blk & 1, q = blk >> 1, qh = q >> 1, qw = q & 1;
    int i = n >> 6, j = n & 63;
    float2 sc = stats[q * 64 + c];
    floatx4 wv = *(const floatx4*)(wy + base);
    size_t xa = ((size_t)(b * 64 + c) * 128 + (qh * 64 + i)) * 128 + qw * 64 + j;
    floatx4 xv = *(const floatx4*)(x + xa);
    floatx4 ov;
#pragma unroll
    for (int k = 0; k < 4; ++k) ov[k] = wv[k] * sc.x + sc.y + xv[k];
    *(floatx4*)(out + xa) = ov;
}

// ---------------------------------------------------------------------------
extern "C" void kernel_launch(void* const* d_in, const int* in_sizes, int n_in,
                              void* d_out, int out_size, void* d_ws, size_t ws_size,
                              hipStream_t stream)
{
    const float* x       = (const float*)d_in[0];
    const float* g_w     = (const float*)d_in[1];
    const float* g_b     = (const float*)d_in[2];
    const float* theta_w = (const float*)d_in[3];
    const float* theta_b = (const float*)d_in[4];
    const float* phi_w   = (const float*)d_in[5];
    const float* phi_b   = (const float*)d_in[6];
    const float* w_w     = (const float*)d_in[7];
    const float* w_b     = (const float*)d_in[8];
    const float* gamma   = (const float*)d_in[9];
    const float* beta    = (const float*)d_in[10];

    char* ws = (char*)d_ws;
    uint16_t* th       = (uint16_t*)(ws);                 // 0 .. 2M
    uint16_t* phT      = (uint16_t*)(ws + (2u << 20));    // 2 .. 4M
    uint16_t* vP       = (uint16_t*)(ws + (4u << 20));    // 4 .. 6M
    float*    wy       = (float*)(ws + (6u << 20));       // 6 .. 14M
    float2*   partials = (float2*)(ws + (14u << 20));     // 256 KB
    float2*   stats    = (float2*)(ws + (14u << 20) + (1u << 18));

    proj_kernel  <<<512,  512, 0, stream>>>(x, theta_w, theta_b, phi_w, phi_b,
                                            g_w, g_b, th, phT, vP);
    flash_kernel <<<512,  512, 0, stream>>>(th, phT, vP, w_w, w_b, wy, partials);
    stats_kernel <<<256,  64,  0, stream>>>(partials, gamma, beta, stats);
    final_kernel <<<2048, 256, 0, stream>>>(wy, stats, x, (float*)d_out);
}

// Round 10
// 123.338 us; speedup vs baseline: 1.1594x; 1.0022x over previous
//
#include <hip/hip_runtime.h>
#include <stdint.h>

typedef __bf16 bf16x8 __attribute__((ext_vector_type(8)));
typedef short  short4v __attribute__((ext_vector_type(4)));   // 4 x bf16 bits
typedef float  floatx4 __attribute__((ext_vector_type(4)));
typedef uint32_t u32x4 __attribute__((ext_vector_type(4)));

#define DI __device__ __forceinline__

// single float -> bf16 bits (compiler-native conversion, RNE)
DI uint16_t bf1(float a) {
    union { __bf16 h; uint16_t u; } r; r.h = (__bf16)a; return r.u;
}

// ---------------------------------------------------------------------------
// Kernel 1: projections via MFMA (r15 structure, green). 512-thread WGs,
// 8 waves = (o-half x pixel-quarter); XCD-clustered blk (bid & 7).
// ---------------------------------------------------------------------------
__global__ __launch_bounds__(512) void proj_kernel(
    const float* __restrict__ x,
    const float* __restrict__ tw, const float* __restrict__ tb,
    const float* __restrict__ pw, const float* __restrict__ pb,
    const float* __restrict__ gw, const float* __restrict__ gb,
    uint16_t* __restrict__ th, uint16_t* __restrict__ phT,
    uint16_t* __restrict__ vP)
{
    __shared__ uint16_t ldsg[32 * 68];     // g-output bounce, pad 68 (8B-align ok)
    int blk = blockIdx.x & 7, nt = blockIdx.x >> 3;
    int tid = threadIdx.x, wid = tid >> 6, lane = tid & 63;
    int quad = lane >> 4, low = lane & 15;
    int pwv = wid & 3, oh = wid >> 2;      // pixel-quarter 0..3, o-half 0..1

    int b = blk & 1, q = blk >> 1, qh = q >> 1, qw = q & 1;
    int pixA = pwv * 16 + low;             // pixel within 64-tile (A-row m=low)
    const float* xg = x + (size_t)b * 1048576 +
                      (size_t)(qh * 64 + nt) * 128 + qw * 64 + pixA;

    // A-frags: A0 = ch 0..31, A1 = ch 32..63;  A[m=low][k=quad*8+j]
    float a0[8], a1[8];
#pragma unroll
    for (int j = 0; j < 8; ++j) {
        a0[j] = xg[(size_t)(quad * 8 + j) * 16384];
        a1[j] = xg[(size_t)(32 + quad * 8 + j) * 16384];
    }
    bf16x8 A0, A1;
#pragma unroll
    for (int j = 0; j < 8; ++j) {
        A0[j] = (__bf16)a0[j];
        A1[j] = (__bf16)a1[j];
    }

    int o = oh * 16 + low;                 // this wave's output channel
    auto dotile = [&](const float* W, const float* Bv) -> floatx4 {
        floatx4 acc;
        float bias = Bv[o];
#pragma unroll
        for (int r = 0; r < 4; ++r) acc[r] = bias;
        const float* wr = W + o * 64 + quad * 8;   // 32B-aligned
        floatx4 w0a = *(const floatx4*)(wr);
        floatx4 w0b = *(const floatx4*)(wr + 4);
        floatx4 w1a = *(const floatx4*)(wr + 32);
        floatx4 w1b = *(const floatx4*)(wr + 36);
        bf16x8 B0, B1;
#pragma unroll
        for (int j = 0; j < 4; ++j) {
            B0[j]     = (__bf16)w0a[j];
            B0[j + 4] = (__bf16)w0b[j];
            B1[j]     = (__bf16)w1a[j];
            B1[j + 4] = (__bf16)w1b[j];
        }
        acc = __builtin_amdgcn_mfma_f32_16x16x32_bf16(A0, B0, acc, 0, 0, 0);
        acc = __builtin_amdgcn_mfma_f32_16x16x32_bf16(A1, B1, acc, 0, 0, 0);
        return acc;
    };

    size_t thbase = ((size_t)blk * 4096 + nt * 64 + pwv * 16 + quad * 4) * 32;

    floatx4 t0 = dotile(tw, tb);
#pragma unroll
    for (int r = 0; r < 4; ++r)
        th[thbase + r * 32 + o] = bf1(t0[r] * 1.44269504088896f);
    floatx4 p0 = dotile(pw, pb);
#pragma unroll
    for (int r = 0; r < 4; ++r)
        phT[thbase + r * 32 + o] = bf1(p0[r]);
    floatx4 g0 = dotile(gw, gb);
#pragma unroll
    for (int r = 0; r < 4; ++r)
        ldsg[o * 68 + pwv * 16 + quad * 4 + r] = bf1(g0[r]);
    __syncthreads();
    // coalesced write-out: thread -> 16B of vP [o=tid>>3][k=(tid&7)*8]
    if (tid < 256) {
        int oo = tid >> 3, k = (tid & 7) * 8;
        const uint16_t* src = &ldsg[oo * 68 + k];
        uint64_t lo = *(const uint64_t*)(src);       // 8B-aligned
        uint64_t hi = *(const uint64_t*)(src + 4);
        union { uint64_t q2[2]; u32x4 v; } out;
        out.q2[0] = lo; out.q2[1] = hi;
        *(u32x4*)(vP + (size_t)blk * 131072 + nt * 2048 + tid * 8) = out.v;
    }
}

// ---------------------------------------------------------------------------
// Kernel 2: fused attention + W-projection + BN partial sums.
// r16 = r12 green structure + isolated s_setprio(1) around the MFMA clusters
// (T5; split-K waves are phase-diverse -> the m191 regime).
// ---------------------------------------------------------------------------
__global__ __launch_bounds__(512, 4) void flash_kernel(
    const uint16_t* __restrict__ th, const uint16_t* __restrict__ phT,
    const uint16_t* __restrict__ vP, const float* __restrict__ w_w,
    const float* __restrict__ w_b, float* __restrict__ wy,
    float2* __restrict__ partials)
{
    __shared__ uint16_t ldsK[4][2][64 * 40];   // [split][buf] 40 KB
    __shared__ uint16_t ldsV[4][2][32 * 72];   // [split][buf] 36 KB
    __shared__ float sred[2][64][2];           // 1 KB  (total ~78 KB -> 2 WG/CU)
    int blk = blockIdx.x & 7;          // XCD-clustered
    int rg  = blockIdx.x >> 3;         // 0..63
    int tid = threadIdx.x, wid = tid >> 6, lane = tid & 63;
    int sp = wid >> 1, qg = wid & 1;   // split 0..3, query-group 0..1
    int lt = tid & 127;                // thread within split (2 waves)
    int quad = lane >> 4, low = lane & 15;
    int n0 = rg * 64 + qg * 32;        // wave's 32-query base

    const uint16_t* thB = th  + (size_t)blk * 131072;
    const uint16_t* kG  = phT + (size_t)blk * 131072;
    const uint16_t* vG  = vP  + (size_t)blk * 131072;

    bf16x8 qfA = *(const bf16x8*)(thB + (n0 + low) * 32 + quad * 8);
    bf16x8 qfB = *(const bf16x8*)(thB + (n0 + 16 + low) * 32 + quad * 8);

    const u32x4* kSrc = (const u32x4*)kG + sp * 4096 + lt;
    const u32x4* vSrc = (const u32x4*)vG + sp * 4096 + lt;
    const int kW0 = ((lt >> 2)) * 40 + (lt & 3) * 8;        // rows 0..31
    const int kW1 = (32 + (lt >> 2)) * 40 + (lt & 3) * 8;   // rows 32..63
    const int vW0 = ((lt >> 3)) * 72 + (lt & 7) * 8;        // o 0..15
    const int vW1 = (16 + (lt >> 3)) * 72 + (lt & 7) * 8;   // o 16..31

    u32x4 kr0 = kSrc[0], kr1 = kSrc[128];
    u32x4 vr0 = vSrc[0], vr1 = vSrc[128];
    *(u32x4*)(&ldsK[sp][0][kW0]) = kr0;  *(u32x4*)(&ldsK[sp][0][kW1]) = kr1;
    *(u32x4*)(&ldsV[sp][0][vW0]) = vr0;  *(u32x4*)(&ldsV[sp][0][vW1]) = vr1;
    __syncthreads();

    floatx4 zero = {0.f, 0.f, 0.f, 0.f};
    floatx4 oaA0 = zero, oaA1 = zero, osA = zero;
    floatx4 oaB0 = zero, oaB1 = zero, osB = zero;
    union { uint32_t u[4]; bf16x8 v; } ones8;
    ones8.u[0] = 0x3F803F80u; ones8.u[1] = 0x3F803F80u;
    ones8.u[2] = 0x3F803F80u; ones8.u[3] = 0x3F803F80u;

    for (int t = 0; t < 16; ++t) {
        int buf = t & 1;
        if (t < 15) {
            kr0 = kSrc[(t + 1) * 256];  kr1 = kSrc[(t + 1) * 256 + 128];
            vr0 = vSrc[(t + 1) * 256];  vr1 = vSrc[(t + 1) * 256 + 128];
        }
        const uint16_t* Kb = ldsK[sp][buf];
        const uint16_t* Vb = ldsV[sp][buf];
        bf16x8 kf[4];
        union { short4v s[2]; bf16x8 v; } vA2[2], vB2[2];
#pragma unroll
        for (int c = 0; c < 4; ++c)
            kf[c] = *(const bf16x8*)(Kb + (c * 16 + low) * 40 + quad * 8);
#pragma unroll
        for (int c2 = 0; c2 < 2; ++c2) {
            vA2[c2].s[0] = *(const short4v*)(Vb + low * 72 + (2*c2)     * 16 + quad * 4);
            vA2[c2].s[1] = *(const short4v*)(Vb + low * 72 + (2*c2 + 1) * 16 + quad * 4);
            vB2[c2].s[0] = *(const short4v*)(Vb + (16 + low) * 72 + (2*c2)     * 16 + quad * 4);
            vB2[c2].s[1] = *(const short4v*)(Vb + (16 + low) * 72 + (2*c2 + 1) * 16 + quad * 4);
        }
        // ---- group A ----
        {
            floatx4 sa[4];
            __builtin_amdgcn_s_setprio(1);
#pragma unroll
            for (int c = 0; c < 4; ++c)
                sa[c] = __builtin_amdgcn_mfma_f32_16x16x32_bf16(kf[c], qfA, zero, 0, 0, 0);
            __builtin_amdgcn_s_setprio(0);
            union { __bf16 h[8]; bf16x8 v; } P2[2];
#pragma unroll
            for (int c2 = 0; c2 < 2; ++c2) {
#pragma unroll
                for (int j = 0; j < 4; ++j) {
                    P2[c2].h[j]     = (__bf16)__builtin_amdgcn_exp2f(sa[2*c2][j]);
                    P2[c2].h[4 + j] = (__bf16)__builtin_amdgcn_exp2f(sa[2*c2 + 1][j]);
                }
            }
            __builtin_amdgcn_s_setprio(1);
#pragma unroll
            for (int c2 = 0; c2 < 2; ++c2) {
                oaA0 = __builtin_amdgcn_mfma_f32_16x16x32_bf16(vA2[c2].v, P2[c2].v, oaA0, 0, 0, 0);
                oaA1 = __builtin_amdgcn_mfma_f32_16x16x32_bf16(vB2[c2].v, P2[c2].v, oaA1, 0, 0, 0);
                osA  = __builtin_amdgcn_mfma_f32_16x16x32_bf16(ones8.v,   P2[c2].v, osA,  0, 0, 0);
            }
            __builtin_amdgcn_s_setprio(0);
        }
        // ---- group B ----
        {
            floatx4 sa[4];
            __builtin_amdgcn_s_setprio(1);
#pragma unroll
            for (int c = 0; c < 4; ++c)
                sa[c] = __builtin_amdgcn_mfma_f32_16x16x32_bf16(kf[c], qfB, zero, 0, 0, 0);
            __builtin_amdgcn_s_setprio(0);
            union { __bf16 h[8]; bf16x8 v; } P2[2];
#pragma unroll
            for (int c2 = 0; c2 < 2; ++c2) {
#pragma unroll
                for (int j = 0; j < 4; ++j) {
                    P2[c2].h[j]     = (__bf16)__builtin_amdgcn_exp2f(sa[2*c2][j]);
                    P2[c2].h[4 + j] = (__bf16)__builtin_amdgcn_exp2f(sa[2*c2 + 1][j]);
                }
            }
            __builtin_amdgcn_s_setprio(1);
#pragma unroll
            for (int c2 = 0; c2 < 2; ++c2) {
                oaB0 = __builtin_amdgcn_mfma_f32_16x16x32_bf16(vA2[c2].v, P2[c2].v, oaB0, 0, 0, 0);
                oaB1 = __builtin_amdgcn_mfma_f32_16x16x32_bf16(vB2[c2].v, P2[c2].v, oaB1, 0, 0, 0);
                osB  = __builtin_amdgcn_mfma_f32_16x16x32_bf16(ones8.v,   P2[c2].v, osB,  0, 0, 0);
            }
            __builtin_amdgcn_s_setprio(0);
        }
        if (t < 15) {
            *(u32x4*)(&ldsK[sp][buf ^ 1][kW0]) = kr0;
            *(u32x4*)(&ldsK[sp][buf ^ 1][kW1]) = kr1;
            *(u32x4*)(&ldsV[sp][buf ^ 1][vW0]) = vr0;
            *(u32x4*)(&ldsV[sp][buf ^ 1][vW1]) = vr1;
        }
        __syncthreads();
    }

    // ---- cross-split combine: 18 floats/thread via reused K-LDS ----
    {
        float* exW = (float*)(&ldsK[0][0][0]);   // 512*18*4B = 36864B <= 40960B
        int li = tid * 18;
#pragma unroll
        for (int r = 0; r < 4; ++r) {
            exW[li + r]      = oaA0[r];
            exW[li + 4 + r]  = oaA1[r];
            exW[li + 9 + r]  = oaB0[r];
            exW[li + 13 + r] = oaB1[r];
        }
        exW[li + 8]  = osA[0];
        exW[li + 17] = osB[0];
    }
    __syncthreads();
    floatx4 cA0 = zero, cA1 = zero, cB0 = zero, cB1 = zero;
    float cosA = 0.f, cosB = 0.f;
    {
        const float* exR = (const float*)(&ldsK[0][0][0]);
#pragma unroll
        for (int s = 0; s < 4; ++s) {
            const float* p = exR + (s * 128 + lt) * 18;
#pragma unroll
            for (int r = 0; r < 4; ++r) {
                cA0[r] += p[r];
                cA1[r] += p[4 + r];
                cB0[r] += p[9 + r];
                cB1[r] += p[13 + r];
            }
            cosA += p[8];
            cosB += p[17];
        }
    }

    // ---- epilogue: normalize, W-projection via one 16x16x32 MFMA each ----
    float rinvA = 1.0f / cosA, rinvB = 1.0f / cosB;
    union { __bf16 h[8]; bf16x8 v; } YA8, YB8;
#pragma unroll
    for (int r = 0; r < 4; ++r) {
        YA8.h[r]     = (__bf16)(cA0[r] * rinvA);
        YA8.h[4 + r] = (__bf16)(cA1[r] * rinvA);
        YB8.h[r]     = (__bf16)(cB0[r] * rinvB);
        YB8.h[4 + r] = (__bf16)(cB1[r] * rinvB);
    }

    float* wyB = wy + (size_t)blk * 262144;
    int nA = n0 + low, nB = n0 + 16 + low;
    int ct = sp;
    {
        floatx4 accA, accB;
#pragma unroll
        for (int r = 0; r < 4; ++r) {
            accA[r] = w_b[ct * 16 + quad * 4 + r];
            accB[r] = accA[r];
        }
        floatx4 w0 = *(const floatx4*)(w_w + (ct * 16 + low) * 32 + quad * 4);
        floatx4 w1 = *(const floatx4*)(w_w + (ct * 16 + low) * 32 + 16 + quad * 4);
        union { __bf16 h[8]; bf16x8 v; } W8;
#pragma unroll
        for (int r = 0; r < 4; ++r) {
            W8.h[r]     = (__bf16)w0[r];
            W8.h[4 + r] = (__bf16)w1[r];
        }
        accA = __builtin_amdgcn_mfma_f32_16x16x32_bf16(W8.v, YA8.v, accA, 0, 0, 0);
        accB = __builtin_amdgcn_mfma_f32_16x16x32_bf16(W8.v, YB8.v, accB, 0, 0, 0);
#pragma unroll
        for (int r = 0; r < 4; ++r) {
            int ch = ct * 16 + quad * 4 + r;
            wyB[(size_t)ch * 4096 + nA] = accA[r];
            wyB[(size_t)ch * 4096 + nB] = accB[r];
            float s = accA[r] + accB[r];
            float ss = accA[r] * accA[r] + accB[r] * accB[r];
            s += __shfl_xor(s, 1); ss += __shfl_xor(ss, 1);
            s += __shfl_xor(s, 2); ss += __shfl_xor(ss, 2);
            s += __shfl_xor(s, 4); ss += __shfl_xor(ss, 4);
            s += __shfl_xor(s, 8); ss += __shfl_xor(ss, 8);
            if (low == 0) {
                sred[qg][ch][0] = s;
                sred[qg][ch][1] = ss;
            }
        }
    }
    __syncthreads();
    if (tid < 64) {
        float s  = sred[0][tid][0] + sred[1][tid][0];
        float ss = sred[0][tid][1] + sred[1][tid][1];
        partials[((size_t)blk * 64 + rg) * 64 + tid] = make_float2(s, ss);
    }
}

// ---------------------------------------------------------------------------
// Kernel 3 (r16): BN stats FUSED into the apply kernel. Each block has a
// constant (q,c): blk=base>>18=bid&7 -> q=(bid&7)>>1; c=((bid>>3)>>2)&63.
// Threads 0..127 load the 128 partials for (q,c), 64-lane shuffle-reduce per
// wave, combine in LDS, broadcast scale/shift, then BN-apply + residual.
// Removes the separate stats kernel + one launch gap.
// ---------------------------------------------------------------------------
__global__ __launch_bounds__(256) void final_kernel(
    const float* __restrict__ wy, const float2* __restrict__ partials,
    const float* __restrict__ gamma, const float* __restrict__ beta,
    const float* __restrict__ x, float* __restrict__ out)
{
    __shared__ float2 ssh[2];
    __shared__ float2 scsh;
    int bid = blockIdx.x;
    int tid = threadIdx.x;
    int qq = (bid & 7) >> 1;
    int cc = (bid >> 5) & 63;              // = ((bid>>3)>>2)&63

    // ---- per-block BN stats for (qq, cc) ----
    float S = 0.f, SS = 0.f;
    if (tid < 128) {
        int b = tid >> 6, rg = tid & 63;
        float2 p = partials[(((size_t)(qq * 2 + b)) * 64 + rg) * 64 + cc];
        S = p.x; SS = p.y;
    }
    S += __shfl_xor(S, 1);  SS += __shfl_xor(SS, 1);
    S += __shfl_xor(S, 2);  SS += __shfl_xor(SS, 2);
    S += __shfl_xor(S, 4);  SS += __shfl_xor(SS, 4);
    S += __shfl_xor(S, 8);  SS += __shfl_xor(SS, 8);
    S += __shfl_xor(S, 16); SS += __shfl_xor(SS, 16);
    S += __shfl_xor(S, 32); SS += __shfl_xor(SS, 32);
    if (tid < 128 && (tid & 63) == 0) ssh[tid >> 6] = make_float2(S, SS);
    __syncthreads();
    if (tid == 0) {
        float St  = ssh[0].x + ssh[1].x;
        float SSt = ssh[0].y + ssh[1].y;
        float mu  = St * (1.0f / 8192.0f);
        float var = SSt * (1.0f / 8192.0f) - mu * mu;
        float scale = gamma[cc] * rsqrtf(var + 1e-5f);
        float shift = beta[cc] - mu * scale;
        scsh = make_float2(scale, shift);
    }
    __syncthreads();
    float2 sc = scsh;

    // ---- BN apply + residual (same mapping as r12/r15 green version) ----
    size_t base = (((size_t)(bid & 7) * 256 + (bid >> 3)) * 256 + tid) * 4;
    int n   = (int)(base & 4095);
    int c   = (int)((base >> 12) & 63);
    int blk = (int)(base >> 18);
    int b = blk & 1, q = blk >> 1, qh = q >> 1, qw = q & 1;
    int i = n >> 6, j = n & 63;
    floatx4 wv = *(const floatx4*)(wy + base);
    size_t xa = ((size_t)(b * 64 + c) * 128 + (qh * 64 + i)) * 128 + qw * 64 + j;
    floatx4 xv = *(const floatx4*)(x + xa);
    floatx4 ov;
#pragma unroll
    for (int k = 0; k < 4; ++k) ov[k] = wv[k] * sc.x + sc.y + xv[k];
    *(floatx4*)(out + xa) = ov;
}

// ---------------------------------------------------------------------------
extern "C" void kernel_launch(void* const* d_in, const int* in_sizes, int n_in,
                              void* d_out, int out_size, void* d_ws, size_t ws_size,
                              hipStream_t stream)
{
    const float* x       = (const float*)d_in[0];
    const float* g_w     = (const float*)d_in[1];
    const float* g_b     = (const float*)d_in[2];
    const float* theta_w = (const float*)d_in[3];
    const float* theta_b = (const float*)d_in[4];
    const float* phi_w   = (const float*)d_in[5];
    const float* phi_b   = (const float*)d_in[6];
    const float* w_w     = (const float*)d_in[7];
    const float* w_b     = (const float*)d_in[8];
    const float* gamma   = (const float*)d_in[9];
    const float* beta    = (const float*)d_in[10];

    char* ws = (char*)d_ws;
    uint16_t* th       = (uint16_t*)(ws);                 // 0 .. 2M
    uint16_t* phT      = (uint16_t*)(ws + (2u << 20));    // 2 .. 4M
    uint16_t* vP       = (uint16_t*)(ws + (4u << 20));    // 4 .. 6M
    float*    wy       = (float*)(ws + (6u << 20));       // 6 .. 14M
    float2*   partials = (float2*)(ws + (14u << 20));     // 64 KB

    proj_kernel  <<<512,  512, 0, stream>>>(x, theta_w, theta_b, phi_w, phi_b,
                                            g_w, g_b, th, phT, vP);
    flash_kernel <<<512,  512, 0, stream>>>(th, phT, vP, w_w, w_b, wy, partials);
    final_kernel <<<2048, 256, 0, stream>>>(wy, partials, gamma, beta, x,
                                            (float*)d_out);
}